// Round 1
// baseline (625.957 us; speedup 1.0000x reference)
//
#include <hip/hip_runtime.h>
#include <cstdint>

#define NQ 4096
#define NKTOT 16448
#define CDIM 256
#define FF 2048

typedef unsigned short u16;
typedef __attribute__((ext_vector_type(8))) short short8;
typedef __attribute__((ext_vector_type(4))) float f32x4;

static __device__ __forceinline__ u16 f2b(float f) {
  union { float f; unsigned u; } v; v.f = f;
  unsigned r = v.u + 0x7fffu + ((v.u >> 16) & 1u);
  return (u16)(r >> 16);
}

static __device__ __forceinline__ f32x4 mfma16(short8 a, short8 b, f32x4 c) {
  return __builtin_amdgcn_mfma_f32_16x16x32_bf16(a, b, c, 0, 0, 0);
}

// ---------------- elementwise kernels ----------------

__global__ void k_f2b(const float* __restrict__ in, u16* __restrict__ out, int n4) {
  int stride = gridDim.x * blockDim.x;
  for (int i = blockIdx.x * blockDim.x + threadIdx.x; i < n4; i += stride) {
    float4 v = ((const float4*)in)[i];
    ushort4 o;
    o.x = f2b(v.x); o.y = f2b(v.y); o.z = f2b(v.z); o.w = f2b(v.w);
    ((ushort4*)out)[i] = o;
  }
}

__global__ void k_copy4(const float* __restrict__ in, float* __restrict__ out, int n4) {
  int stride = gridDim.x * blockDim.x;
  for (int i = blockIdx.x * blockDim.x + threadIdx.x; i < n4; i += stride) {
    ((float4*)out)[i] = ((const float4*)in)[i];
  }
}

__global__ __launch_bounds__(256)
void k_ln(const float* __restrict__ x, const float* __restrict__ w,
          const float* __restrict__ b, u16* __restrict__ out, int M) {
  int row = blockIdx.x * 4 + (threadIdx.x >> 6);
  int lane = threadIdx.x & 63;
  const float4 v = ((const float4*)(x + (size_t)row * CDIM))[lane];
  float s = v.x + v.y + v.z + v.w;
  float s2 = v.x * v.x + v.y * v.y + v.z * v.z + v.w * v.w;
  #pragma unroll
  for (int d = 1; d < 64; d <<= 1) { s += __shfl_xor(s, d); s2 += __shfl_xor(s2, d); }
  float mean = s * (1.0f / CDIM);
  float rstd = rsqrtf(s2 * (1.0f / CDIM) - mean * mean + 1e-5f);
  float4 wv = ((const float4*)w)[lane];
  float4 bv = ((const float4*)b)[lane];
  ushort4 o;
  o.x = f2b((v.x - mean) * rstd * wv.x + bv.x);
  o.y = f2b((v.y - mean) * rstd * wv.y + bv.y);
  o.z = f2b((v.z - mean) * rstd * wv.z + bv.z);
  o.w = f2b((v.w - mean) * rstd * wv.w + bv.w);
  ((ushort4*)(out + (size_t)row * CDIM))[lane] = o;
}

// rope: out[2p]   = f00*x0 + f01*x1 ; out[2p+1] = f10*x0 + f11*x1
// rows >= (limit_base - *nkxp) are copied unroped. freqs row index = row % 4096.
__global__ void k_rope(const float* __restrict__ in, const float* __restrict__ fr,
                       u16* __restrict__ out, int M, const int* __restrict__ nkxp,
                       int limit_base) {
  int idx = blockIdx.x * blockDim.x + threadIdx.x;
  if (idx >= M * 128) return;
  int row = idx >> 7, p = idx & 127;
  int limit = limit_base - (nkxp ? *nkxp : 0);
  float x0 = in[(size_t)row * CDIM + 2 * p];
  float x1 = in[(size_t)row * CDIM + 2 * p + 1];
  float o0, o1;
  if (row < limit) {
    float4 f = ((const float4*)fr)[((size_t)(row & 4095)) * 128 + p];
    o0 = f.x * x0 + f.y * x1;
    o1 = f.z * x0 + f.w * x1;
  } else { o0 = x0; o1 = x1; }
  out[(size_t)row * CDIM + 2 * p]     = f2b(o0);
  out[(size_t)row * CDIM + 2 * p + 1] = f2b(o1);
}

// ---------------- GEMM: out[M,N] = A[M,K] @ W[N,K]^T + bias (+Cadd) (gelu?) ----------------

template<int GELU, int HASADD, int OUTBF>
__global__ __launch_bounds__(256)
void k_gemm(const u16* __restrict__ A, const u16* __restrict__ W,
            const float* __restrict__ bias, const float* __restrict__ Cadd,
            void* __restrict__ outp, int M, int N, int K) {
  __shared__ u16 As[64][72];
  __shared__ u16 Ws[64][72];
  const int bm = blockIdx.y * 64, bn = blockIdx.x * 64;
  const int tid = threadIdx.x;
  const int lane = tid & 63, wid = tid >> 6;
  const int r16 = lane & 15, g = lane >> 4;
  const int wm = (wid >> 1) * 32, wn = (wid & 1) * 32;
  f32x4 acc[2][2];
  #pragma unroll
  for (int i = 0; i < 2; ++i)
    #pragma unroll
    for (int j = 0; j < 2; ++j)
      #pragma unroll
      for (int r = 0; r < 4; ++r) acc[i][j][r] = 0.0f;
  const int srow = tid >> 2, scol = (tid & 3) * 16;
  for (int k0 = 0; k0 < K; k0 += 64) {
    const short8* sa = (const short8*)(A + (size_t)(bm + srow) * K + k0 + scol);
    *(short8*)(&As[srow][scol])     = sa[0];
    *(short8*)(&As[srow][scol + 8]) = sa[1];
    const short8* sw = (const short8*)(W + (size_t)(bn + srow) * K + k0 + scol);
    *(short8*)(&Ws[srow][scol])     = sw[0];
    *(short8*)(&Ws[srow][scol + 8]) = sw[1];
    __syncthreads();
    #pragma unroll
    for (int kc = 0; kc < 2; ++kc) {
      short8 a0 = *(const short8*)(&As[wm + r16][kc * 32 + g * 8]);
      short8 a1 = *(const short8*)(&As[wm + 16 + r16][kc * 32 + g * 8]);
      short8 b0 = *(const short8*)(&Ws[wn + r16][kc * 32 + g * 8]);
      short8 b1 = *(const short8*)(&Ws[wn + 16 + r16][kc * 32 + g * 8]);
      acc[0][0] = mfma16(a0, b0, acc[0][0]);
      acc[0][1] = mfma16(a0, b1, acc[0][1]);
      acc[1][0] = mfma16(a1, b0, acc[1][0]);
      acc[1][1] = mfma16(a1, b1, acc[1][1]);
    }
    __syncthreads();
  }
  #pragma unroll
  for (int tr = 0; tr < 2; ++tr)
    #pragma unroll
    for (int tc = 0; tc < 2; ++tc)
      #pragma unroll
      for (int r = 0; r < 4; ++r) {
        int row = bm + wm + tr * 16 + g * 4 + r;
        int col = bn + wn + tc * 16 + r16;
        float v = acc[tr][tc][r] + bias[col];
        if (HASADD) v += Cadd[(size_t)row * N + col];
        if (GELU) v = 0.5f * v * (1.0f + erff(v * 0.70710678118654752f));
        if (OUTBF) ((u16*)outp)[(size_t)row * N + col] = f2b(v);
        else ((float*)outp)[(size_t)row * N + col] = v;
      }
}

// ---------------- flash attention (1 head, hd=256), KV-split partials ----------------
// grid (NQ/64, SPLIT); block 256 = 4 waves; wave owns 16 q-rows; KV tile = 32 keys.

__global__ __launch_bounds__(256)
void k_flash(const u16* __restrict__ Q, const u16* __restrict__ Kb, const u16* __restrict__ Vb,
             float* __restrict__ Opart, float* __restrict__ mpart, float* __restrict__ lpart,
             int NT, int SPLIT, float scale) {
  __shared__ u16 Ks[32][264];
  __shared__ u16 Vt[256][40];   // V transposed: Vt[dim][kv]
  __shared__ u16 Ps[4][16][40]; // per-wave P tile
  const int qb = blockIdx.x, s = blockIdx.y;
  const int tid = threadIdx.x, lane = tid & 63, wid = tid >> 6;
  const int r16 = lane & 15, g = lane >> 4;
  short8 qf[8];
  const size_t qrow = (size_t)qb * 64 + wid * 16 + r16;
  #pragma unroll
  for (int kc = 0; kc < 8; ++kc)
    qf[kc] = *(const short8*)(Q + qrow * CDIM + kc * 32 + g * 8);
  float m_run[4], l_run[4];
  #pragma unroll
  for (int r = 0; r < 4; ++r) { m_run[r] = -3e38f; l_run[r] = 0.0f; }
  f32x4 oacc[16];
  #pragma unroll
  for (int i = 0; i < 16; ++i)
    #pragma unroll
    for (int r = 0; r < 4; ++r) oacc[i][r] = 0.0f;
  const int krow_st = tid >> 3, kcol_st = (tid & 7) * 32;
  const int vrow_st = tid & 31, vcc0 = tid >> 5;
  for (int t = s; t < NT; t += SPLIT) {
    const size_t kbase = (size_t)t * 32;
    // stage K row-major
    const short8* ksrc = (const short8*)(Kb + (kbase + krow_st) * CDIM + kcol_st);
    #pragma unroll
    for (int j = 0; j < 4; ++j)
      *(short8*)(&Ks[krow_st][kcol_st + j * 8]) = ksrc[j];
    // stage V transposed
    #pragma unroll
    for (int j = 0; j < 4; ++j) {
      int cch = j * 8 + vcc0;
      short8 vv = *(const short8*)(Vb + (kbase + vrow_st) * CDIM + cch * 8);
      const u16* pv = (const u16*)&vv;
      #pragma unroll
      for (int u = 0; u < 8; ++u) Vt[cch * 8 + u][vrow_st] = pv[u];
    }
    __syncthreads();
    // S = Q K^T  (2 col-tiles of 16 keys)
    f32x4 sacc[2];
    #pragma unroll
    for (int ct = 0; ct < 2; ++ct) {
      #pragma unroll
      for (int r = 0; r < 4; ++r) sacc[ct][r] = 0.0f;
      #pragma unroll
      for (int kc = 0; kc < 8; ++kc) {
        short8 kf = *(const short8*)(&Ks[ct * 16 + r16][kc * 32 + g * 8]);
        sacc[ct] = mfma16(qf[kc], kf, sacc[ct]);
      }
    }
    // online softmax (rows = g*4+r, this lane holds cols {r16, 16+r16})
    float p0[4], p1[4], cf[4];
    #pragma unroll
    for (int r = 0; r < 4; ++r) {
      float s0 = sacc[0][r] * scale, s1 = sacc[1][r] * scale;
      float mx = fmaxf(s0, s1);
      #pragma unroll
      for (int d = 1; d < 16; d <<= 1) mx = fmaxf(mx, __shfl_xor(mx, d));
      float mn = fmaxf(m_run[r], mx);
      cf[r] = __expf(m_run[r] - mn);
      p0[r] = __expf(s0 - mn);
      p1[r] = __expf(s1 - mn);
      float rs = p0[r] + p1[r];
      #pragma unroll
      for (int d = 1; d < 16; d <<= 1) rs += __shfl_xor(rs, d);
      l_run[r] = l_run[r] * cf[r] + rs;
      m_run[r] = mn;
    }
    #pragma unroll
    for (int ct = 0; ct < 16; ++ct)
      #pragma unroll
      for (int r = 0; r < 4; ++r) oacc[ct][r] *= cf[r];
    // P -> LDS (bf16), per-wave region
    #pragma unroll
    for (int r = 0; r < 4; ++r) {
      Ps[wid][g * 4 + r][r16]      = f2b(p0[r]);
      Ps[wid][g * 4 + r][16 + r16] = f2b(p1[r]);
    }
    short8 pa = *(const short8*)(&Ps[wid][r16][g * 8]);
    // O += P V   (16 dim-tiles, single K=32 mfma each)
    #pragma unroll
    for (int ct = 0; ct < 16; ++ct) {
      short8 vf = *(const short8*)(&Vt[ct * 16 + r16][g * 8]);
      oacc[ct] = mfma16(pa, vf, oacc[ct]);
    }
    __syncthreads();
  }
  const size_t ob = ((size_t)s * NQ + (size_t)qb * 64 + wid * 16) * CDIM;
  #pragma unroll
  for (int ct = 0; ct < 16; ++ct)
    #pragma unroll
    for (int r = 0; r < 4; ++r)
      Opart[ob + (size_t)(g * 4 + r) * CDIM + ct * 16 + r16] = oacc[ct][r];
  if (r16 == 0) {
    #pragma unroll
    for (int r = 0; r < 4; ++r) {
      int row = qb * 64 + wid * 16 + g * 4 + r;
      mpart[(size_t)s * NQ + row] = m_run[r];
      lpart[(size_t)s * NQ + row] = l_run[r];
    }
  }
}

__global__ void k_combine(const float* __restrict__ Opart, const float* __restrict__ mpart,
                          const float* __restrict__ lpart, u16* __restrict__ out, int SPLIT) {
  int row = blockIdx.x, col = threadIdx.x;
  float M = -3e38f;
  for (int s = 0; s < SPLIT; ++s) M = fmaxf(M, mpart[(size_t)s * NQ + row]);
  float L = 0.0f, acc = 0.0f;
  for (int s = 0; s < SPLIT; ++s) {
    float w = __expf(mpart[(size_t)s * NQ + row] - M);
    L += lpart[(size_t)s * NQ + row] * w;
    acc += w * Opart[((size_t)s * NQ + row) * CDIM + col];
  }
  out[(size_t)row * CDIM + col] = f2b(acc / L);
}

// ---------------- host ----------------

typedef void (*GemmFn)(const u16*, const u16*, const float*, const float*, void*, int, int, int);

extern "C" void kernel_launch(void* const* d_in, const int* in_sizes, int n_in,
                              void* d_out, int out_size, void* d_ws, size_t ws_size,
                              hipStream_t stream) {
  const float* image  = (const float*)d_in[0];
  const float* x      = (const float*)d_in[1];
  const float* mpos   = (const float*)d_in[4];
  const float* ropeT  = (const float*)d_in[5];
  const int*   nkx    = (const int*)d_in[6];

  char* ws = (char*)d_ws;
  size_t off = 0;
  auto alloc = [&](size_t bytes) -> void* {
    void* p = ws + off;
    off += (bytes + 255) & ~(size_t)255;
    return p;
  };
  const size_t nq_c = (size_t)NQ * CDIM;     // 1048576
  const size_t nk_c = (size_t)NKTOT * CDIM;  // 4210688
  const size_t nq_ff = (size_t)NQ * FF;      // 8388608

  u16* w_sa_q = (u16*)alloc(65536 * 2);
  u16* w_sa_k = (u16*)alloc(65536 * 2);
  u16* w_sa_v = (u16*)alloc(65536 * 2);
  u16* w_sa_o = (u16*)alloc(65536 * 2);
  u16* w_ca_q = (u16*)alloc(65536 * 2);
  u16* w_ca_k = (u16*)alloc(65536 * 2);
  u16* w_ca_v = (u16*)alloc(65536 * 2);
  u16* w_ca_o = (u16*)alloc(65536 * 2);
  u16* w_ica_q = (u16*)alloc(65536 * 2);
  u16* w_ica_k = (u16*)alloc(65536 * 2);
  u16* w_l1 = (u16*)alloc(524288 * 2);
  u16* w_l2 = (u16*)alloc(524288 * 2);
  u16* img16  = (u16*)alloc(nq_c * 2);
  u16* mimg16 = (u16*)alloc(nk_c * 2);
  u16* mem16  = (u16*)alloc(nk_c * 2);
  u16* nbuf   = (u16*)alloc(nq_c * 2);
  float* qf   = (float*)alloc(nq_c * 4);  // SA q f32; later CA qtmp
  float* kf   = (float*)alloc(nq_c * 4);  // SA k f32; later CA q2
  float* ktmp = (float*)alloc(nk_c * 4);  // CA k pass1; later Opart_CA; later h16
  float* k2f  = (float*)alloc(nk_c * 4);  // CA k pass2; earlier Opart_SA
  u16* qr16  = (u16*)alloc(nq_c * 2);     // SA q roped; later CA q roped
  u16* kr16  = (u16*)alloc(nq_c * 2);
  u16* v16   = (u16*)alloc(nq_c * 2);
  u16* k2r16 = (u16*)alloc(nk_c * 2);
  u16* v216  = (u16*)alloc(nk_c * 2);
  u16* ao16  = (u16*)alloc(nq_c * 2);     // attn out; reused for CA
  float* x1  = (float*)alloc(nq_c * 4);
  float* x2  = (float*)alloc(nq_c * 4);
  float* mpart = (float*)alloc((size_t)4 * NQ * 4);
  float* lpart = (float*)alloc((size_t)4 * NQ * 4);
  u16* h16 = (u16*)ktmp;          // MLP hidden (bf16) overlays ktmp
  float* opart_sa = k2f;          // SA O-partials overlay k2f (not yet live)
  float* opart_ca = ktmp;         // CA O-partials overlay ktmp (dead by then)
  float* out_img = (float*)d_out;
  float* out_x   = (float*)d_out + nq_c;

  auto cvt = [&](const void* src, u16* dst, size_t n) {
    int n4 = (int)(n / 4);
    int blocks = (n4 + 255) / 256; if (blocks > 2048) blocks = 2048;
    k_f2b<<<dim3(blocks), dim3(256), 0, stream>>>((const float*)src, dst, n4);
  };
  auto gemm = [&](GemmFn fn, const u16* A, const u16* W, const void* bias,
                  const float* cadd, void* out, int M, int N, int K) {
    fn<<<dim3(N / 64, M / 64), dim3(256), 0, stream>>>(A, W, (const float*)bias, cadd, out, M, N, K);
  };

  // convert weights + fp32 activations to bf16
  cvt(d_in[7],  w_sa_q, 65536);  cvt(d_in[9],  w_sa_k, 65536);
  cvt(d_in[11], w_sa_v, 65536);  cvt(d_in[13], w_sa_o, 65536);
  cvt(d_in[15], w_ca_q, 65536);  cvt(d_in[17], w_ca_k, 65536);
  cvt(d_in[19], w_ca_v, 65536);  cvt(d_in[21], w_ca_o, 65536);
  cvt(d_in[23], w_ica_q, 65536); cvt(d_in[25], w_ica_k, 65536);
  cvt(d_in[27], w_l1, 524288);   cvt(d_in[29], w_l2, 524288);
  cvt(d_in[0], img16, nq_c);
  cvt(d_in[2], mimg16, nk_c);
  cvt(d_in[3], mem16, nk_c);

  // ---- self-attention block ----
  k_ln<<<dim3(NQ / 4), dim3(256), 0, stream>>>(x, (const float*)d_in[31], (const float*)d_in[32], nbuf, NQ);
  gemm(k_gemm<0,0,0>, nbuf, w_sa_q, d_in[8],  nullptr, qf,  NQ, CDIM, CDIM);
  gemm(k_gemm<0,0,0>, nbuf, w_sa_k, d_in[10], nullptr, kf,  NQ, CDIM, CDIM);
  gemm(k_gemm<0,0,1>, nbuf, w_sa_v, d_in[12], nullptr, v16, NQ, CDIM, CDIM);
  int rblocks = (NQ * 128 + 255) / 256;
  k_rope<<<dim3(rblocks), dim3(256), 0, stream>>>(qf, ropeT, qr16, NQ, (const int*)nullptr, NQ);
  k_rope<<<dim3(rblocks), dim3(256), 0, stream>>>(kf, ropeT, kr16, NQ, (const int*)nullptr, NQ);
  k_flash<<<dim3(NQ / 64, 4), dim3(256), 0, stream>>>(qr16, kr16, v16, opart_sa, mpart, lpart, NQ / 32, 4, 0.0625f);
  k_combine<<<dim3(NQ), dim3(256), 0, stream>>>(opart_sa, mpart, lpart, ao16, 4);
  gemm(k_gemm<0,1,0>, ao16, w_sa_o, d_in[14], x, x1, NQ, CDIM, CDIM);

  // ---- cross-attention block ----
  k_ln<<<dim3(NQ / 4), dim3(256), 0, stream>>>(x1, (const float*)d_in[33], (const float*)d_in[34], nbuf, NQ);
  gemm(k_gemm<0,0,0>, img16, w_ica_q, d_in[24], nullptr, qf, NQ, CDIM, CDIM);
  gemm(k_gemm<0,1,0>, nbuf,  w_ca_q,  d_in[16], qf, kf, NQ, CDIM, CDIM);
  k_rope<<<dim3(rblocks), dim3(256), 0, stream>>>(kf, ropeT, qr16, NQ, (const int*)nullptr, NQ);
  gemm(k_gemm<0,1,0>, mimg16, w_ica_k, d_in[26], mpos, ktmp, NKTOT, CDIM, CDIM);
  gemm(k_gemm<0,1,0>, mem16,  w_ca_k,  d_in[18], ktmp, k2f, NKTOT, CDIM, CDIM);
  int rblocks2 = (NKTOT * 128 + 255) / 256;
  k_rope<<<dim3(rblocks2), dim3(256), 0, stream>>>(k2f, ropeT, k2r16, NKTOT, nkx, NKTOT);
  gemm(k_gemm<0,0,1>, mem16, w_ca_v, d_in[20], nullptr, v216, NKTOT, CDIM, CDIM);
  k_flash<<<dim3(NQ / 64, 4), dim3(256), 0, stream>>>(qr16, k2r16, v216, opart_ca, mpart, lpart, NKTOT / 32, 4, 0.0625f);
  k_combine<<<dim3(NQ), dim3(256), 0, stream>>>(opart_ca, mpart, lpart, ao16, 4);
  gemm(k_gemm<0,1,0>, ao16, w_ca_o, d_in[22], x1, x2, NQ, CDIM, CDIM);

  // ---- MLP block ----
  k_ln<<<dim3(NQ / 4), dim3(256), 0, stream>>>(x2, (const float*)d_in[35], (const float*)d_in[36], nbuf, NQ);
  gemm(k_gemm<1,0,1>, nbuf, w_l1, d_in[28], nullptr, h16, NQ, FF, CDIM);
  gemm(k_gemm<0,1,0>, h16,  w_l2, d_in[30], x2, out_x, NQ, CDIM, FF);

  // ---- image passthrough ----
  int cblocks = ((int)(nq_c / 4) + 255) / 256; if (cblocks > 2048) cblocks = 2048;
  k_copy4<<<dim3(cblocks), dim3(256), 0, stream>>>(image, out_img, (int)(nq_c / 4));
}